// Round 6
// baseline (60.839 us; speedup 1.0000x reference)
//
#include <hip/hip_runtime.h>

// ACT-R activation recurrence — EDF-balanced tile schedule.
// s_i = sum_{j<i} ((t_i-t_j)*H)^(-decay_j),  decay_j = w0 + w1*s_j  (s_0=0)
// (reference's max(diff*H,1) never binds: min gap 0.05 days * 2160 = 108)
// out[i-1,b] = sigmoid((ln(s_i)-TAU)/S), i=1..L-1.
//
// Identity: diff^(-decay_j) = exp2(q_ij*alpha_j), q_ij = -w1*log2(diff_ij),
// alpha = s + w0/w1; masked triangle entries q=-1e30 -> term 0.
//
// Tile grid: row-blocks r, col-blocks c (64x64), c<r. Tile (r,c) is legal in
// any phase p in [c+1, r-1] (col c final after triangle(c); needed before
// triangle(r)). Previous kernels ran every tile at p=c+1 (front-loaded: phase-1
// panel ~6k cyc, phase-14 ~0 -> ~48% idle). This kernel spreads the 105
// deferred tiles 7-8/phase via a static EDF schedule; same-row collisions
// within a phase are resolved with LDS atomicAdd. Strip handles (k,k-1)
// just-in-time; wave 0 runs the serial 64-step triangle.

constexpr int   L  = 1024;
constexpr int   B  = 256;
constexpr int   T  = 64;
constexpr int   NT = 1024;   // 16 waves

constexpr float H_CONST = 86400.0f * 0.025f;   // 2160
constexpr float TAU_C   = -0.704205679427144f;
constexpr float S_C     = 0.254893976981164f;
constexpr float LN2     = 0.69314718055994530942f;
constexpr float LOG2E   = 1.4426950408889634074f;
constexpr float BIGNEG  = -1e30f;

// EDF tile schedule: phases 1..14, tiles (r,c) with c <= r-2, window [c+1,r-1].
__device__ static const unsigned char TRr[105] = {
  2,3,4,5,6,7,8,9,
  3,4,5,6,7,8,9,
  4,5,6,7,8,9,10,10,
  5,6,7,8,9,10,10,11,
  6,7,8,9,10,11,11,11,
  7,8,9,10,11,11,12,12,
  8,9,10,11,12,12,12,13,
  9,10,11,12,12,12,13,13,
  10,11,12,13,13,13,13,14,
  11,12,13,13,13,14,14,14,
  12,13,14,14,14,14,15,15,
  13,14,14,14,14,15,15,15,
  14,15,15,15,15,15,15,15,
  15,15};
__device__ static const unsigned char TCc[105] = {
  0,0,0,0,0,0,0,0,
  1,1,1,1,1,1,1,
  2,2,2,2,2,2,0,1,
  3,3,3,3,3,2,3,0,
  4,4,4,4,4,1,2,3,
  5,5,5,5,4,5,0,1,
  6,6,6,6,2,3,4,0,
  7,7,7,5,6,7,1,2,
  8,8,8,3,4,5,6,0,
  9,9,7,8,9,1,2,3,
  10,10,4,5,6,7,0,1,
  11,8,9,10,11,2,3,4,
  12,5,6,7,8,9,10,11,
  12,13};
__device__ static const unsigned short POFF[17] =
  {0,0,8,15,23,31,39,47,55,63,71,79,87,95,103,105,105};

__device__ __forceinline__ float flog2(float x) { return __builtin_amdgcn_logf(x); }
__device__ __forceinline__ float fexp2(float x) { return __builtin_amdgcn_exp2f(x); }
__device__ __forceinline__ float rdlane(float v, int l) {
    return __uint_as_float(__builtin_amdgcn_readlane(__float_as_uint(v), l));
}

#define LOADCH(p0, p1, p2, p3, c)                                   \
    p0 = *(const float4*)(qb + 4 * ((4 * (c) + 0) ^ xk));           \
    p1 = *(const float4*)(qb + 4 * ((4 * (c) + 1) ^ xk));           \
    p2 = *(const float4*)(qb + 4 * ((4 * (c) + 2) ^ xk));           \
    p3 = *(const float4*)(qb + 4 * ((4 * (c) + 3) ^ xk));

#define RUN4(qv, J)                                                  \
    { float sg;                                                      \
      sg = rdlane(alpha, (J) + 0); alpha += fexp2(qv.x * sg);        \
      sg = rdlane(alpha, (J) + 1); alpha += fexp2(qv.y * sg);        \
      sg = rdlane(alpha, (J) + 2); alpha += fexp2(qv.z * sg);        \
      sg = rdlane(alpha, (J) + 3); alpha += fexp2(qv.w * sg); }

#define RUN16(q0, q1, q2, q3, J) \
    RUN4(q0, J) RUN4(q1, (J) + 4) RUN4(q2, (J) + 8) RUN4(q3, (J) + 12)

__global__ __launch_bounds__(NT)
void actr_kernel(const float* __restrict__ sp, const float* __restrict__ w,
                 float* __restrict__ out)
{
    __shared__ float  tH[L];
    __shared__ float  acc[L];       // partial sums from deferred tiles
    __shared__ float2 col[L];       // finalized columns {t_j, -decay_j}
    __shared__ float  qT[2][T * T]; // triangle q, swizzled row-major
    __shared__ float  stripsum[T];

    const int b    = blockIdx.x;
    const int tid  = threadIdx.x;
    const int lane = tid & 63;
    const int wv   = tid >> 6;
    const float w0  = w[0];
    const float w1  = w[1];
    const float CSH = w0 / w1;

    for (int i = tid; i < L; i += NT) {
        tH[i]  = sp[i * B + b] * H_CONST;
        acc[i] = 0.0f;
    }
    if (tid < T) stripsum[tid] = 0.0f;
    __syncthreads();

    // prologue: build qT[0] for block 0
    for (int f = tid; f < T * T; f += NT) {
        const int j = f & 63, l2 = f >> 6;
        const float q = (j < l2) ? (-w1 * flog2(tH[l2] - tH[j])) : BIGNEG;
        qT[0][l2 * 64 + (j ^ (4 * (l2 & 15)))] = q;
    }
    __syncthreads();

    for (int k = 0; k < L / T; ++k) {
        const int I0 = k * T;
        const int xk = lane & 15;
        const float* qb = &qT[k & 1][lane * 64];

        float4 qA0, qA1, qA2, qA3, qB0, qB1, qB2, qB3;
        float  acc_r = 0.0f;
        if (wv == 0) {
            LOADCH(qA0, qA1, qA2, qA3, 0)       // hidden under strip
            acc_r = acc[I0 + lane];             // final since barrier of k-1
        }

        // strip: cols k-1 -> block-k rows; all 1024 threads, 16/row
        if (k > 0) {
            const int rl = tid >> 4, c = tid & 15;
            const float my_t = tH[I0 + rl];
            const float2* cb = &col[I0 - T];
            float p = 0.0f;
            #pragma unroll
            for (int uu = 0; uu < 4; ++uu) {
                const float2 cj = cb[c + 16 * uu];
                p += fexp2(cj.y * flog2(my_t - cj.x));
            }
            p += __shfl_xor(p, 1);
            p += __shfl_xor(p, 2);
            p += __shfl_xor(p, 4);
            p += __shfl_xor(p, 8);
            if (c == 0) stripsum[rl] = p;
        }
        __syncthreads();

        if (wv == 0) {
            // serial triangle: pure-register chain
            float alpha = acc_r + stripsum[lane] + CSH;
            __builtin_amdgcn_s_setprio(1);
            LOADCH(qB0, qB1, qB2, qB3, 1)
            RUN16(qA0, qA1, qA2, qA3, 0)
            LOADCH(qA0, qA1, qA2, qA3, 2)
            RUN16(qB0, qB1, qB2, qB3, 16)
            LOADCH(qB0, qB1, qB2, qB3, 3)
            RUN16(qA0, qA1, qA2, qA3, 32)
            RUN16(qB0, qB1, qB2, qB3, 48)
            __builtin_amdgcn_s_setprio(0);
            const int r = I0 + lane;
            col[r] = make_float2(tH[r], -w1 * alpha);
            if (r > 0) {
                const float act = flog2(alpha - CSH) * LN2;   // ln(s_r)
                const float e   = fexp2((TAU_C - act) * (LOG2E / S_C));
                out[(r - 1) * B + b] = 1.0f / (1.0f + e);
            }
        } else {
            // deferred tiles for this phase (EDF schedule), quarter-tile units:
            // 16 rows x 64 cols; 4 lanes/row, each lane 2-col stripes via float4
            const int wp = wv - 1;                    // 0..14
            const int QT = 4 * (POFF[k + 1] - POFF[k]);
            const int wpe = (wp + k) % 15;            // rotate straggler
            for (int h = wpe; h < QT; h += 15) {
                const int t     = POFF[k] + (h >> 2);
                const int rl    = 64 * (int)TRr[t] + 16 * (h & 3) + (lane >> 2);
                const int cbb   = 64 * (int)TCc[t];
                const float my_t = tH[rl];
                const float4* cp = reinterpret_cast<const float4*>(&col[cbb]);
                float a = 0.0f;
                #pragma unroll
                for (int u = 0; u < 8; ++u) {
                    const float4 c2 = cp[4 * u + (lane & 3)];
                    a += fexp2(c2.y * flog2(my_t - c2.x));
                    a += fexp2(c2.w * flog2(my_t - c2.z));
                }
                a += __shfl_xor(a, 1);
                a += __shfl_xor(a, 2);
                if ((lane & 3) == 0) atomicAdd(&acc[rl], a);
            }
            // build next block's triangle q (timestamps only)
            if (k < L / T - 1) {
                const int I1 = I0 + T;
                float* qn = &qT[(k + 1) & 1][0];
                const float vt = tH[I1 + lane];
                #pragma unroll
                for (int m = 0; m < 5; ++m) {
                    const int l2 = (wv - 1) + 15 * m;
                    if (l2 < 64) {
                        const float tl2 = rdlane(vt, l2);
                        const float q = (lane < l2) ? (-w1 * flog2(tl2 - vt))
                                                    : BIGNEG;
                        qn[l2 * 64 + (lane ^ (4 * (l2 & 15)))] = q;
                    }
                }
            }
        }
        __syncthreads();
    }
}

extern "C" void kernel_launch(void* const* d_in, const int* in_sizes, int n_in,
                              void* d_out, int out_size, void* d_ws, size_t ws_size,
                              hipStream_t stream) {
    const float* sp = (const float*)d_in[0];
    const float* w  = (const float*)d_in[1];
    float* out      = (float*)d_out;
    actr_kernel<<<dim3(B), dim3(NT), 0, stream>>>(sp, w, out);
}